// Round 5
// baseline (1629.690 us; speedup 1.0000x reference)
//
#include <hip/hip_runtime.h>
#include <hip/hip_bf16.h>

typedef __bf16 bf16_t;
typedef __bf16 bf16x8 __attribute__((ext_vector_type(8)));
typedef float  f32x4  __attribute__((ext_vector_type(4)));

constexpr int T_ = 2048, H_ = 2048, I_ = 5632, E_ = 8, S_ = T_ * 2;

// ---- workspace layout (bytes) ----  total ~88.2 MB
constexpr size_t OFF_HB    = 0;                                   // bf16 hidden  [T][H]
constexpr size_t OFF_HOUT  = OFF_HB    + (size_t)T_ * H_ * 2;     // bf16 h       [S][I]
constexpr size_t OFF_DPART = OFF_HOUT  + (size_t)S_ * I_ * 2;     // f32 downpart [S][H]
constexpr size_t OFF_TOS   = OFF_DPART + (size_t)S_ * H_ * 4;     // int token_of_slot[S]
constexpr size_t OFF_SOT   = OFF_TOS   + (size_t)S_ * 4;          // int slot_of_tk[T*2]
constexpr size_t OFF_TKI   = OFF_SOT   + (size_t)S_ * 4;          // int topk_idx[T*2]
constexpr size_t OFF_TKW   = OFF_TKI   + (size_t)S_ * 4;          // f32 topk_w[T*2]
constexpr size_t OFF_CNT   = OFF_TKW   + (size_t)S_ * 4;          // int counts[E]
constexpr size_t OFF_OFFS  = OFF_CNT   + 64;                      // int offs[E]
constexpr size_t OFF_CUR   = OFF_OFFS  + 64;                      // int cursor[E]

// async global->LDS, 16B per lane. LDS dest = wave-uniform base + lane*16 (HW).
__device__ __forceinline__ void gload16(const void* g, void* l) {
  __builtin_amdgcn_global_load_lds(
      (const __attribute__((address_space(1))) void*)g,
      (__attribute__((address_space(3))) void*)l, 16, 0, 0);
}

// asm-pinned global load: volatile + "memory" -> compiler cannot sink/remat it.
__device__ __forceinline__ f32x4 gld4(const float* p) {
  f32x4 r;
  asm volatile("global_load_dwordx4 %0, %1, off" : "=&v"(r) : "v"(p) : "memory");
  return r;
}

__device__ __forceinline__ bf16x8 cvt8(f32x4 a, f32x4 b) {
  bf16x8 r;
  r[0]=(bf16_t)a[0]; r[1]=(bf16_t)a[1]; r[2]=(bf16_t)a[2]; r[3]=(bf16_t)a[3];
  r[4]=(bf16_t)b[0]; r[5]=(bf16_t)b[1]; r[6]=(bf16_t)b[2]; r[7]=(bf16_t)b[3];
  return r;
}

#define VM_WAIT0()  do { asm volatile("s_waitcnt vmcnt(0)" ::: "memory"); \
                         __builtin_amdgcn_sched_barrier(0); } while (0)

// ================= router: logits, softmax, top-2, bf16 convert =================
__global__ __launch_bounds__(256)
void router_kernel(const float* __restrict__ hs, const float* __restrict__ gw,
                   int* __restrict__ tki, float* __restrict__ tkw,
                   int* __restrict__ counts, bf16_t* __restrict__ hb)
{
  const int t = blockIdx.x;
  const int tid = threadIdx.x;
  const int lane = tid & 63, wid = tid >> 6;
  const float* hrow = hs + (size_t)t * H_;
  const int c0 = tid * 8;
  float4 h0 = *(const float4*)(hrow + c0);
  float4 h1 = *(const float4*)(hrow + c0 + 4);
  bf16x8 hv;
  hv[0]=(bf16_t)h0.x; hv[1]=(bf16_t)h0.y; hv[2]=(bf16_t)h0.z; hv[3]=(bf16_t)h0.w;
  hv[4]=(bf16_t)h1.x; hv[5]=(bf16_t)h1.y; hv[6]=(bf16_t)h1.z; hv[7]=(bf16_t)h1.w;
  *(bf16x8*)(hb + (size_t)t * H_ + c0) = hv;

  float acc[E_];
  #pragma unroll
  for (int e = 0; e < E_; ++e) {
    const float* g = gw + (size_t)e * H_ + c0;
    float4 g0 = *(const float4*)(g);
    float4 g1 = *(const float4*)(g + 4);
    acc[e] = h0.x*g0.x + h0.y*g0.y + h0.z*g0.z + h0.w*g0.w
           + h1.x*g1.x + h1.y*g1.y + h1.z*g1.z + h1.w*g1.w;
  }
  #pragma unroll
  for (int e = 0; e < E_; ++e)
    #pragma unroll
    for (int o = 32; o > 0; o >>= 1)
      acc[e] += __shfl_down(acc[e], o);
  __shared__ float red[4][E_];
  if (lane == 0)
    #pragma unroll
    for (int e = 0; e < E_; ++e) red[wid][e] = acc[e];
  __syncthreads();
  if (tid == 0) {
    float l[E_];
    #pragma unroll
    for (int e = 0; e < E_; ++e) l[e] = red[0][e] + red[1][e] + red[2][e] + red[3][e];
    float m = l[0];
    #pragma unroll
    for (int e = 1; e < E_; ++e) m = fmaxf(m, l[e]);
    float p[E_]; float s = 0.f;
    #pragma unroll
    for (int e = 0; e < E_; ++e) { p[e] = __expf(l[e] - m); s += p[e]; }
    int i1 = 0;
    #pragma unroll
    for (int e = 1; e < E_; ++e) if (l[e] > l[i1]) i1 = e;
    int i2 = (i1 == 0) ? 1 : 0;
    #pragma unroll
    for (int e = 0; e < E_; ++e) if (e != i1 && l[e] > l[i2]) i2 = e;
    tki[2*t] = i1; tki[2*t+1] = i2;
    tkw[2*t] = p[i1] / s; tkw[2*t+1] = p[i2] / s;
    atomicAdd(&counts[i1], 1);
    atomicAdd(&counts[i2], 1);
  }
}

// ================= scan: expert offsets + slot lists =================
__global__ void scan_kernel(const int* __restrict__ counts, const int* __restrict__ tki,
                            int* __restrict__ offs, int* __restrict__ cursor,
                            int* __restrict__ tos, int* __restrict__ sot)
{
  if (threadIdx.x == 0) {
    int run = 0;
    for (int e = 0; e < E_; ++e) { offs[e] = run; cursor[e] = run; run += counts[e]; }
  }
  __syncthreads();
  for (int t = threadIdx.x; t < T_; t += blockDim.x) {
    #pragma unroll
    for (int k = 0; k < 2; ++k) {
      int e = tki[2*t + k];
      int s = atomicAdd(&cursor[e], 1);
      tos[s] = t;
      sot[2*t + k] = s;
    }
  }
}

// ================= GEMM1: gathered hidden x w1^T, dual (gate,up), fused silu*mul =================
// BK=64 dbuf. A: global_load_lds, pre-swizzled source. B: asm-pinned global loads (issued
// BEFORE compute, drained by ONE vmcnt(0) AFTER compute) -> cvt bf16 -> swizzled ds_write.
// Swizzle invariant (128B rows): LDS(r, byte b) = tile(r, b ^ ((r&7)<<4)).
constexpr int G1_BM = 128, G1_BN = 64, G1_BK = 64;

__global__ __launch_bounds__(256, 2)
void gemm1_kernel(const bf16_t* __restrict__ hb, const float* __restrict__ w1,
                  const int* __restrict__ tos, const int* __restrict__ offs,
                  const int* __restrict__ counts, bf16_t* __restrict__ hout)
{
  // XCD-chunked raster: expert e pinned to XCD (bid&7); m-tiles innermost for L2 strip reuse.
  const int bid = blockIdx.x;
  const int e   = bid & 7;
  const int idx = bid >> 3;          // 16 m-tiles x 88 n-tiles
  const int mt  = idx & 15;
  const int nt  = idx >> 4;

  const int cnt = counts[e];
  const int m0 = mt * G1_BM;
  if (m0 >= cnt) return;
  const int off = offs[e];
  const int n0 = nt * G1_BN;

  const float* Wg = w1 + (size_t)e * (2 * (size_t)I_ * H_) + (size_t)n0 * H_;

  __shared__ bf16_t Al [2][G1_BM][G1_BK];   // 32 KB
  __shared__ bf16_t Bld[2][2 * G1_BN][G1_BK]; // rows 0-63 gate, 64-127 up; 32 KB

  const int tid = threadIdx.x;
  const int lane = tid & 63, wid = tid >> 6;
  const int wm = wid >> 1, wn = wid & 1;
  const int l15 = lane & 15, l4 = lane >> 4;

  // --- A: 16 chunks of 1KB (8 rows x 128B); lane -> row q*8+(lane>>3), src slot pre-swizzled.
  const bf16_t* agp[4]; int aoff[4];
  #pragma unroll
  for (int i = 0; i < 4; ++i) {
    int q = wid * 4 + i;
    int row = q * 8 + (lane >> 3);
    int slot = off + m0 + row, mx = off + cnt - 1;
    if (slot > mx) slot = mx;            // clamp pad rows (masked at store)
    agp[i]  = hb + (size_t)tos[slot] * H_ + ((lane & 7) ^ (lane >> 3)) * 8;
    aoff[i] = q * 1024;
  }
  auto stageA = [&](int b, int k0) {
    char* ab = (char*)&Al[b][0][0];
    #pragma unroll
    for (int i = 0; i < 4; ++i) gload16(agp[i] + k0, ab + aoff[i]);
  };

  // --- B: thread covers row brow=tid>>1 (0-63 gate, 64-127 up), f32 col half bh=tid&1.
  const int brow = tid >> 1, bh = tid & 1;
  const size_t browIdx = (brow < 64) ? (size_t)brow : (size_t)(I_ + brow - 64);
  const float* bbase = Wg + browIdx * H_ + bh * 32;
  int wby[4];
  #pragma unroll
  for (int c = 0; c < 4; ++c)
    wby[c] = brow * 128 + ((64 * bh + 16 * c) ^ ((brow & 7) << 4));

  f32x4 br[8];
  auto loadB = [&](int k0) {
    #pragma unroll
    for (int j = 0; j < 8; ++j) br[j] = gld4(bbase + k0 + 4 * j);
  };
  auto writeB = [&](int b) {
    char* bb = (char*)&Bld[b][0][0];
    #pragma unroll
    for (int c = 0; c < 4; ++c)
      *(bf16x8*)(bb + wby[c]) = cvt8(br[2*c], br[2*c+1]);
  };

  f32x4 accg[4][2], accu[4][2];
  #pragma unroll
  for (int mi = 0; mi < 4; ++mi)
    #pragma unroll
    for (int ni = 0; ni < 2; ++ni) {
      accg[mi][ni] = f32x4{0.f,0.f,0.f,0.f};
      accu[mi][ni] = f32x4{0.f,0.f,0.f,0.f};
    }

  auto compute = [&](int b) {
    const char* ab = (const char*)&Al [b][0][0];
    const char* bb = (const char*)&Bld[b][0][0];
    #pragma unroll
    for (int ks = 0; ks < 2; ++ks) {
      const int cb = ks * 64 + l4 * 16;
      bf16x8 af[4], bgf[2], buf2[2];
      #pragma unroll
      for (int mi = 0; mi < 4; ++mi) {
        int r = wm * 64 + mi * 16 + l15;
        af[mi] = *(const bf16x8*)(ab + r * 128 + (cb ^ ((r & 7) << 4)));
      }
      #pragma unroll
      for (int ni = 0; ni < 2; ++ni) {
        int rg = wn * 32 + ni * 16 + l15;
        int o  = cb ^ ((rg & 7) << 4);
        bgf[ni]  = *(const bf16x8*)(bb + rg * 128 + o);
        buf2[ni] = *(const bf16x8*)(bb + (rg + 64) * 128 + o);   // (rg+64)&7 == rg&7
      }
      #pragma unroll
      for (int mi = 0; mi < 4; ++mi)
        #pragma unroll
        for (int ni = 0; ni < 2; ++ni) {
          accg[mi][ni] = __builtin_amdgcn_mfma_f32_16x16x32_bf16(af[mi], bgf[ni],  accg[mi][ni], 0, 0, 0);
          accu[mi][ni] = __builtin_amdgcn_mfma_f32_16x16x32_bf16(af[mi], buf2[ni], accu[mi][ni], 0, 0, 0);
        }
    }
  };

  constexpr int NK = H_ / G1_BK;   // 32
  stageA(0, 0); loadB(0);
  VM_WAIT0();
  writeB(0);
  __syncthreads();
  int cur = 0;
  for (int kt = 0; kt < NK; ++kt) {
    if (kt + 1 < NK) { stageA(cur ^ 1, (kt + 1) * G1_BK); loadB((kt + 1) * G1_BK); }
    compute(cur);                  // full compute phase overlaps the in-flight loads
    VM_WAIT0();                    // ONE drain per K-step (A->LDS nxt + B regs nxt)
    if (kt + 1 < NK) writeB(cur ^ 1);
    __syncthreads();
    cur ^= 1;
  }

  // epilogue: silu(g)*u -> bf16 h[slot][i]   (C/D map: row=(lane>>4)*4+j, col=lane&15)
  #pragma unroll
  for (int mi = 0; mi < 4; ++mi)
    #pragma unroll
    for (int ni = 0; ni < 2; ++ni)
      #pragma unroll
      for (int j = 0; j < 4; ++j) {
        int rel = wm*64 + mi*16 + l4*4 + j;
        if (m0 + rel < cnt) {
          int col = n0 + wn*32 + ni*16 + l15;
          float g = accg[mi][ni][j];
          float u = accu[mi][ni][j];
          float hvv = (g / (1.0f + __expf(-g))) * u;
          hout[(size_t)(off + m0 + rel) * I_ + col] = (bf16_t)hvv;
        }
      }
}

// ================= GEMM2: h x w2^T -> per-slot partial (f32) =================
constexpr int G2_BM = 128, G2_BN = 128, G2_BK = 64;

__global__ __launch_bounds__(256, 2)
void gemm2_kernel(const bf16_t* __restrict__ hbuf, const float* __restrict__ w2,
                  const int* __restrict__ offs, const int* __restrict__ counts,
                  float* __restrict__ dpart)
{
  const int bid = blockIdx.x;
  const int e   = bid & 7;
  const int idx = bid >> 3;          // 16 m x 16 n
  const int mt  = idx & 15;
  const int nt  = idx >> 4;

  const int cnt = counts[e];
  const int m0 = mt * G2_BM;
  if (m0 >= cnt) return;
  const int off = offs[e];
  const int n0 = nt * G2_BN;
  const float* W = w2 + (size_t)e * ((size_t)H_ * I_) + (size_t)n0 * I_;

  __shared__ bf16_t Al[2][G2_BM][G2_BK];   // 32 KB
  __shared__ bf16_t Bl[2][G2_BN][G2_BK];   // 32 KB

  const int tid = threadIdx.x;
  const int lane = tid & 63, wid = tid >> 6;
  const int wm = wid >> 1, wn = wid & 1;
  const int l15 = lane & 15, l4 = lane >> 4;

  const bf16_t* agp[4]; int aoff[4];
  #pragma unroll
  for (int i = 0; i < 4; ++i) {
    int q = wid * 4 + i;
    int row = q * 8 + (lane >> 3);
    int slot = off + m0 + row, mx = off + cnt - 1;
    if (slot > mx) slot = mx;
    agp[i]  = hbuf + (size_t)slot * I_ + ((lane & 7) ^ (lane >> 3)) * 8;
    aoff[i] = q * 1024;
  }
  auto stageA = [&](int b, int k0) {
    char* ab = (char*)&Al[b][0][0];
    #pragma unroll
    for (int i = 0; i < 4; ++i) gload16(agp[i] + k0, ab + aoff[i]);
  };

  const int brow = tid >> 1, bh = tid & 1;
  const float* bbase = W + (size_t)brow * I_ + bh * 32;
  int wby[4];
  #pragma unroll
  for (int c = 0; c < 4; ++c)
    wby[c] = brow * 128 + ((64 * bh + 16 * c) ^ ((brow & 7) << 4));

  f32x4 br[8];
  auto loadB = [&](int k0) {
    #pragma unroll
    for (int j = 0; j < 8; ++j) br[j] = gld4(bbase + k0 + 4 * j);
  };
  auto writeB = [&](int b) {
    char* bb = (char*)&Bl[b][0][0];
    #pragma unroll
    for (int c = 0; c < 4; ++c)
      *(bf16x8*)(bb + wby[c]) = cvt8(br[2*c], br[2*c+1]);
  };

  f32x4 acc[4][4];
  #pragma unroll
  for (int mi = 0; mi < 4; ++mi)
    #pragma unroll
    for (int ni = 0; ni < 4; ++ni) acc[mi][ni] = f32x4{0.f,0.f,0.f,0.f};

  auto compute = [&](int b) {
    const char* ab = (const char*)&Al[b][0][0];
    const char* bb = (const char*)&Bl[b][0][0];
    #pragma unroll
    for (int ks = 0; ks < 2; ++ks) {
      const int cb = ks * 64 + l4 * 16;
      bf16x8 af[4], bf[4];
      #pragma unroll
      for (int mi = 0; mi < 4; ++mi) {
        int r = wm * 64 + mi * 16 + l15;
        af[mi] = *(const bf16x8*)(ab + r * 128 + (cb ^ ((r & 7) << 4)));
      }
      #pragma unroll
      for (int ni = 0; ni < 4; ++ni) {
        int r = wn * 64 + ni * 16 + l15;
        bf[ni] = *(const bf16x8*)(bb + r * 128 + (cb ^ ((r & 7) << 4)));
      }
      #pragma unroll
      for (int mi = 0; mi < 4; ++mi)
        #pragma unroll
        for (int ni = 0; ni < 4; ++ni)
          acc[mi][ni] = __builtin_amdgcn_mfma_f32_16x16x32_bf16(af[mi], bf[ni], acc[mi][ni], 0, 0, 0);
    }
  };

  constexpr int NK = I_ / G2_BK;   // 88
  stageA(0, 0); loadB(0);
  VM_WAIT0();
  writeB(0);
  __syncthreads();
  int cur = 0;
  for (int kt = 0; kt < NK; ++kt) {
    if (kt + 1 < NK) { stageA(cur ^ 1, (kt + 1) * G2_BK); loadB((kt + 1) * G2_BK); }
    compute(cur);
    VM_WAIT0();
    if (kt + 1 < NK) writeB(cur ^ 1);
    __syncthreads();
    cur ^= 1;
  }

  #pragma unroll
  for (int mi = 0; mi < 4; ++mi)
    #pragma unroll
    for (int ni = 0; ni < 4; ++ni)
      #pragma unroll
      for (int j = 0; j < 4; ++j) {
        int rel = wm*64 + mi*16 + l4*4 + j;
        if (m0 + rel < cnt) {
          int col = n0 + wn*64 + ni*16 + l15;
          dpart[(size_t)(off + m0 + rel) * H_ + col] = acc[mi][ni][j];
        }
      }
}

// ================= combine: out[t] = w0*d[s0] + w1*d[s1] =================
__global__ __launch_bounds__(256)
void combine_kernel(const float* __restrict__ dpart, const int* __restrict__ sot,
                    const float* __restrict__ tkw, float* __restrict__ out)
{
  int idx = blockIdx.x * 256 + threadIdx.x;     // T*H/4 total
  int t = idx >> 9;                              // H/4 = 512
  int c = (idx & 511) * 4;
  float wA = tkw[2*t], wB = tkw[2*t+1];
  int sA = sot[2*t], sB = sot[2*t+1];
  float4 a = *(const float4*)(dpart + (size_t)sA * H_ + c);
  float4 b = *(const float4*)(dpart + (size_t)sB * H_ + c);
  float4 o;
  o.x = wA*a.x + wB*b.x; o.y = wA*a.y + wB*b.y;
  o.z = wA*a.z + wB*b.z; o.w = wA*a.w + wB*b.w;
  *(float4*)(out + (size_t)t * H_ + c) = o;
}

extern "C" void kernel_launch(void* const* d_in, const int* in_sizes, int n_in,
                              void* d_out, int out_size, void* d_ws, size_t ws_size,
                              hipStream_t stream) {
  const float* hs = (const float*)d_in[0];
  const float* gw = (const float*)d_in[1];
  const float* w1 = (const float*)d_in[2];
  const float* w2 = (const float*)d_in[3];
  float* out = (float*)d_out;
  char* ws = (char*)d_ws;

  bf16_t* hb    = (bf16_t*)(ws + OFF_HB);
  bf16_t* hout  = (bf16_t*)(ws + OFF_HOUT);
  float*  dpart = (float*) (ws + OFF_DPART);
  int*    tos   = (int*)   (ws + OFF_TOS);
  int*    sot   = (int*)   (ws + OFF_SOT);
  int*    tki   = (int*)   (ws + OFF_TKI);
  float*  tkw   = (float*) (ws + OFF_TKW);
  int*    cnt   = (int*)   (ws + OFF_CNT);
  int*    offp  = (int*)   (ws + OFF_OFFS);
  int*    curp  = (int*)   (ws + OFF_CUR);

  hipMemsetAsync(ws + OFF_CNT, 0, 64, stream);   // zero expert counts each call

  router_kernel<<<T_, 256, 0, stream>>>(hs, gw, tki, tkw, cnt, hb);
  scan_kernel<<<1, 256, 0, stream>>>(cnt, tki, offp, curp, tos, sot);
  gemm1_kernel<<<(T_ / G1_BM) * (I_ / G1_BN) * E_, 256, 0, stream>>>(hb, w1, tos, offp, cnt, hout);
  gemm2_kernel<<<(T_ / G2_BM) * (H_ / G2_BN) * E_, 256, 0, stream>>>(hout, w2, offp, cnt, dpart);
  combine_kernel<<<(T_ * H_ / 4) / 256, 256, 0, stream>>>(dpart, sot, tkw, out);
}

// Round 6
// 849.289 us; speedup vs baseline: 1.9189x; 1.9189x over previous
//
#include <hip/hip_runtime.h>
#include <hip/hip_bf16.h>

typedef __bf16 bf16_t;
typedef __bf16 bf16x8 __attribute__((ext_vector_type(8)));
typedef float  f32x4  __attribute__((ext_vector_type(4)));

constexpr int T_ = 2048, H_ = 2048, I_ = 5632, E_ = 8, S_ = T_ * 2;

// ---- workspace layout (bytes) ----  total ~88.2 MB
constexpr size_t OFF_HB    = 0;                                   // bf16 hidden  [T][H]
constexpr size_t OFF_HOUT  = OFF_HB    + (size_t)T_ * H_ * 2;     // bf16 h       [S][I]
constexpr size_t OFF_DPART = OFF_HOUT  + (size_t)S_ * I_ * 2;     // f32 downpart [S][H]
constexpr size_t OFF_TOS   = OFF_DPART + (size_t)S_ * H_ * 4;     // int token_of_slot[S]
constexpr size_t OFF_SOT   = OFF_TOS   + (size_t)S_ * 4;          // int slot_of_tk[T*2]
constexpr size_t OFF_TKI   = OFF_SOT   + (size_t)S_ * 4;          // int topk_idx[T*2]
constexpr size_t OFF_TKW   = OFF_TKI   + (size_t)S_ * 4;          // f32 topk_w[T*2]
constexpr size_t OFF_CNT   = OFF_TKW   + (size_t)S_ * 4;          // int counts[E]
constexpr size_t OFF_OFFS  = OFF_CNT   + 64;                      // int offs[E]
constexpr size_t OFF_CUR   = OFF_OFFS  + 64;                      // int cursor[E]

// async global->LDS, 16B per lane. LDS dest = wave-uniform base + lane*16 (HW).
// No VGPR result => nothing for the register allocator to spill or sink.
__device__ __forceinline__ void gload16(const void* g, void* l) {
  __builtin_amdgcn_global_load_lds(
      (const __attribute__((address_space(1))) void*)g,
      (__attribute__((address_space(3))) void*)l, 16, 0, 0);
}

__device__ __forceinline__ bf16x8 cvt8(f32x4 a, f32x4 b) {
  bf16x8 r;
  r[0]=(bf16_t)a[0]; r[1]=(bf16_t)a[1]; r[2]=(bf16_t)a[2]; r[3]=(bf16_t)a[3];
  r[4]=(bf16_t)b[0]; r[5]=(bf16_t)b[1]; r[6]=(bf16_t)b[2]; r[7]=(bf16_t)b[3];
  return r;
}

// ================= router: logits, softmax, top-2, bf16 convert =================
__global__ __launch_bounds__(256)
void router_kernel(const float* __restrict__ hs, const float* __restrict__ gw,
                   int* __restrict__ tki, float* __restrict__ tkw,
                   int* __restrict__ counts, bf16_t* __restrict__ hb)
{
  const int t = blockIdx.x;
  const int tid = threadIdx.x;
  const int lane = tid & 63, wid = tid >> 6;
  const float* hrow = hs + (size_t)t * H_;
  const int c0 = tid * 8;
  float4 h0 = *(const float4*)(hrow + c0);
  float4 h1 = *(const float4*)(hrow + c0 + 4);
  bf16x8 hv;
  hv[0]=(bf16_t)h0.x; hv[1]=(bf16_t)h0.y; hv[2]=(bf16_t)h0.z; hv[3]=(bf16_t)h0.w;
  hv[4]=(bf16_t)h1.x; hv[5]=(bf16_t)h1.y; hv[6]=(bf16_t)h1.z; hv[7]=(bf16_t)h1.w;
  *(bf16x8*)(hb + (size_t)t * H_ + c0) = hv;

  float acc[E_];
  #pragma unroll
  for (int e = 0; e < E_; ++e) {
    const float* g = gw + (size_t)e * H_ + c0;
    float4 g0 = *(const float4*)(g);
    float4 g1 = *(const float4*)(g + 4);
    acc[e] = h0.x*g0.x + h0.y*g0.y + h0.z*g0.z + h0.w*g0.w
           + h1.x*g1.x + h1.y*g1.y + h1.z*g1.z + h1.w*g1.w;
  }
  #pragma unroll
  for (int e = 0; e < E_; ++e)
    #pragma unroll
    for (int o = 32; o > 0; o >>= 1)
      acc[e] += __shfl_down(acc[e], o);
  __shared__ float red[4][E_];
  if (lane == 0)
    #pragma unroll
    for (int e = 0; e < E_; ++e) red[wid][e] = acc[e];
  __syncthreads();
  if (tid == 0) {
    float l[E_];
    #pragma unroll
    for (int e = 0; e < E_; ++e) l[e] = red[0][e] + red[1][e] + red[2][e] + red[3][e];
    float m = l[0];
    #pragma unroll
    for (int e = 1; e < E_; ++e) m = fmaxf(m, l[e]);
    float p[E_]; float s = 0.f;
    #pragma unroll
    for (int e = 0; e < E_; ++e) { p[e] = __expf(l[e] - m); s += p[e]; }
    int i1 = 0;
    #pragma unroll
    for (int e = 1; e < E_; ++e) if (l[e] > l[i1]) i1 = e;
    int i2 = (i1 == 0) ? 1 : 0;
    #pragma unroll
    for (int e = 0; e < E_; ++e) if (e != i1 && l[e] > l[i2]) i2 = e;
    tki[2*t] = i1; tki[2*t+1] = i2;
    tkw[2*t] = p[i1] / s; tkw[2*t+1] = p[i2] / s;
    atomicAdd(&counts[i1], 1);
    atomicAdd(&counts[i2], 1);
  }
}

// ================= scan: expert offsets + slot lists =================
__global__ void scan_kernel(const int* __restrict__ counts, const int* __restrict__ tki,
                            int* __restrict__ offs, int* __restrict__ cursor,
                            int* __restrict__ tos, int* __restrict__ sot)
{
  if (threadIdx.x == 0) {
    int run = 0;
    for (int e = 0; e < E_; ++e) { offs[e] = run; cursor[e] = run; run += counts[e]; }
  }
  __syncthreads();
  for (int t = threadIdx.x; t < T_; t += blockDim.x) {
    #pragma unroll
    for (int k = 0; k < 2; ++k) {
      int e = tki[2*t + k];
      int s = atomicAdd(&cursor[e], 1);
      tos[s] = t;
      sot[2*t + k] = s;
    }
  }
}

// ================= GEMM1: gathered hidden x w1^T, dual (gate,up), fused silu*mul =================
// Depth-3 multibuffer, counted vmcnt (never 0 in main loop), all staging via global_load_lds.
// Per K-step: raw_barrier; stage(t+2) [6 loads/wave]; s_waitcnt vmcnt(12); raw_barrier; compute(t).
// Loads stay 2 K-steps in flight across barriers -> no bulk DRAM stall (T3/T4, m218).
// BK=32. LDS/buf: A bf16 [128][32] 8KB + B f32 [128 rows: 64 gate + 64 up][32] 16KB = 24KB; x3 = 72KB.
// Swizzles (both-sides, rule #21): A slot4 ^= (row>>1)&3 (2-way, free); B slot8 ^= row&7 (2-way, free).
constexpr int G1_BM = 128, G1_BN = 64, G1_BK = 32;
constexpr int G1_BUF = G1_BM * G1_BK * 2 + 2 * G1_BN * G1_BK * 4;   // 24576

__global__ __launch_bounds__(256, 2)
void gemm1_kernel(const bf16_t* __restrict__ hb, const float* __restrict__ w1,
                  const int* __restrict__ tos, const int* __restrict__ offs,
                  const int* __restrict__ counts, bf16_t* __restrict__ hout)
{
  // XCD-chunked raster: expert e pinned to XCD (bid&7); m-tiles innermost for L2 strip reuse.
  const int bid = blockIdx.x;
  const int e   = bid & 7;
  const int idx = bid >> 3;          // 16 m-tiles x 88 n-tiles
  const int mt  = idx & 15;
  const int nt  = idx >> 4;

  const int cnt = counts[e];
  const int m0 = mt * G1_BM;
  if (m0 >= cnt) return;
  const int off = offs[e];
  const int n0 = nt * G1_BN;

  const float* Wg = w1 + (size_t)e * (2 * (size_t)I_ * H_) + (size_t)n0 * H_;

  __shared__ char smem[3 * G1_BUF];   // 72KB -> 2 blocks/CU

  const int tid = threadIdx.x;
  const int lane = tid & 63, wid = tid >> 6;
  const int wm = wid >> 1, wn = wid & 1;
  const int l15 = lane & 15, l4 = lane >> 4;

  // --- A staging: 8 chunks of 1KB (16 rows x 64B); wave stages chunks wid*2+{0,1}.
  // lane -> LDS row q*16+(lane>>2), slot lane&3; source slot pre-swizzled ^((row>>1)&3).
  const bf16_t* agp[2]; int aoff[2];
  #pragma unroll
  for (int i = 0; i < 2; ++i) {
    int q = wid * 2 + i;
    int row = q * 16 + (lane >> 2);
    int slot = off + m0 + row, mx = off + cnt - 1;
    if (slot > mx) slot = mx;            // clamp pad rows (masked at store)
    agp[i]  = hb + (size_t)tos[slot] * H_ + ((lane & 3) ^ ((lane >> 3) & 3)) * 8;
    aoff[i] = q * 1024;
  }
  // --- B staging (f32): 16 chunks of 1KB (8 rows x 128B); wave stages chunks wid*4+{0..3}.
  // LDS rows 0-63 = gate n0.., 64-127 = up n0..; source slot pre-swizzled ^(row&7).
  const float* bgp[4]; int boff[4];
  #pragma unroll
  for (int i = 0; i < 4; ++i) {
    int q = wid * 4 + i;
    int lrow = q * 8 + (lane >> 3);
    size_t wr = (lrow < 64) ? (size_t)lrow : (size_t)(I_ - 64 + lrow);
    bgp[i]  = Wg + wr * H_ + ((lane & 7) ^ ((lane >> 3) & 7)) * 4;
    boff[i] = q * 1024;
  }

  auto stage = [&](int b, int t) {
    char* ab = smem + b * G1_BUF;
    char* bb = ab + 8192;
    const int k0 = t * G1_BK;
    #pragma unroll
    for (int i = 0; i < 2; ++i) gload16(agp[i] + k0, ab + aoff[i]);
    #pragma unroll
    for (int i = 0; i < 4; ++i) gload16(bgp[i] + k0, bb + boff[i]);
  };

  f32x4 accg[4][2], accu[4][2];
  #pragma unroll
  for (int mi = 0; mi < 4; ++mi)
    #pragma unroll
    for (int ni = 0; ni < 2; ++ni) {
      accg[mi][ni] = f32x4{0.f,0.f,0.f,0.f};
      accu[mi][ni] = f32x4{0.f,0.f,0.f,0.f};
    }

  auto compute = [&](int b) {
    const char* ab = smem + b * G1_BUF;
    const char* bb = ab + 8192;
    bf16x8 af[4], bgf[2], buf2[2];
    const int as = (l4 ^ ((l15 >> 1) & 3)) * 16;       // A swizzled slot byte
    #pragma unroll
    for (int mi = 0; mi < 4; ++mi) {
      int r = wm * 64 + mi * 16 + l15;
      af[mi] = *(const bf16x8*)(ab + r * 64 + as);
    }
    const int s0 = ((2 * l4) ^ (l15 & 7)) * 16;        // B swizzled slot byte
    #pragma unroll
    for (int ni = 0; ni < 2; ++ni) {
      int rg = wn * 32 + ni * 16 + l15;
      const char* rowg = bb + rg * 128;
      const char* rowu = bb + (rg + 64) * 128;
      f32x4 g0 = *(const f32x4*)(rowg + s0);
      f32x4 g1 = *(const f32x4*)(rowg + (s0 ^ 16));
      f32x4 u0 = *(const f32x4*)(rowu + s0);
      f32x4 u1 = *(const f32x4*)(rowu + (s0 ^ 16));
      bgf[ni]  = cvt8(g0, g1);
      buf2[ni] = cvt8(u0, u1);
    }
    #pragma unroll
    for (int mi = 0; mi < 4; ++mi)
      #pragma unroll
      for (int ni = 0; ni < 2; ++ni) {
        accg[mi][ni] = __builtin_amdgcn_mfma_f32_16x16x32_bf16(af[mi], bgf[ni],  accg[mi][ni], 0, 0, 0);
        accu[mi][ni] = __builtin_amdgcn_mfma_f32_16x16x32_bf16(af[mi], buf2[ni], accu[mi][ni], 0, 0, 0);
      }
  };

  constexpr int NK = H_ / G1_BK;   // 64
  stage(0, 0); stage(1, 1);        // 12 loads/wave in flight
  int bs = 2, bc = 0;
  for (int t = 0; t < NK - 2; ++t) {
    __builtin_amdgcn_s_barrier();                       // all waves done reading buf[bs]
    stage(bs, t + 2);                                   // 18 in flight
    asm volatile("s_waitcnt vmcnt(12)" ::: "memory");   // stage(t) landed (per-wave)
    __builtin_amdgcn_s_barrier();                       // landed for ALL waves
    __builtin_amdgcn_sched_barrier(0);
    compute(bc);
    bs = (bs == 2) ? 0 : bs + 1;
    bc = (bc == 2) ? 0 : bc + 1;
  }
  __builtin_amdgcn_s_barrier();
  asm volatile("s_waitcnt vmcnt(6)" ::: "memory");
  __builtin_amdgcn_s_barrier();
  __builtin_amdgcn_sched_barrier(0);
  compute(bc);
  bc = (bc == 2) ? 0 : bc + 1;
  __builtin_amdgcn_s_barrier();
  asm volatile("s_waitcnt vmcnt(0)" ::: "memory");
  __builtin_amdgcn_s_barrier();
  __builtin_amdgcn_sched_barrier(0);
  compute(bc);

  // epilogue: silu(g)*u -> bf16 h[slot][i]   (C/D map: row=(lane>>4)*4+j, col=lane&15)
  #pragma unroll
  for (int mi = 0; mi < 4; ++mi)
    #pragma unroll
    for (int ni = 0; ni < 2; ++ni)
      #pragma unroll
      for (int j = 0; j < 4; ++j) {
        int rel = wm*64 + mi*16 + l4*4 + j;
        if (m0 + rel < cnt) {
          int col = n0 + wn*32 + ni*16 + l15;
          float g = accg[mi][ni][j];
          float u = accu[mi][ni][j];
          float hvv = (g / (1.0f + __expf(-g))) * u;
          hout[(size_t)(off + m0 + rel) * I_ + col] = (bf16_t)hvv;
        }
      }
}

// ================= GEMM2: h x w2^T -> per-slot partial (f32) =================
// Same depth-3 counted-vmcnt structure. LDS/buf: A bf16 [128][32] 8KB + B f32 [128][32] 16KB.
constexpr int G2_BM = 128, G2_BN = 128, G2_BK = 32;
constexpr int G2_BUF = G2_BM * G2_BK * 2 + G2_BN * G2_BK * 4;   // 24576

__global__ __launch_bounds__(256, 2)
void gemm2_kernel(const bf16_t* __restrict__ hbuf, const float* __restrict__ w2,
                  const int* __restrict__ offs, const int* __restrict__ counts,
                  float* __restrict__ dpart)
{
  const int bid = blockIdx.x;
  const int e   = bid & 7;
  const int idx = bid >> 3;          // 16 m x 16 n
  const int mt  = idx & 15;
  const int nt  = idx >> 4;

  const int cnt = counts[e];
  const int m0 = mt * G2_BM;
  if (m0 >= cnt) return;
  const int off = offs[e];
  const int n0 = nt * G2_BN;
  const float* W = w2 + (size_t)e * ((size_t)H_ * I_) + (size_t)n0 * I_;

  __shared__ char smem[3 * G2_BUF];   // 72KB

  const int tid = threadIdx.x;
  const int lane = tid & 63, wid = tid >> 6;
  const int wm = wid >> 1, wn = wid & 1;
  const int l15 = lane & 15, l4 = lane >> 4;

  const bf16_t* agp[2]; int aoff[2];
  #pragma unroll
  for (int i = 0; i < 2; ++i) {
    int q = wid * 2 + i;
    int row = q * 16 + (lane >> 2);
    int slot = off + m0 + row, mx = off + cnt - 1;
    if (slot > mx) slot = mx;
    agp[i]  = hbuf + (size_t)slot * I_ + ((lane & 3) ^ ((lane >> 3) & 3)) * 8;
    aoff[i] = q * 1024;
  }
  const float* bgp[4]; int boff[4];
  #pragma unroll
  for (int i = 0; i < 4; ++i) {
    int q = wid * 4 + i;
    int lrow = q * 8 + (lane >> 3);
    bgp[i]  = W + (size_t)lrow * I_ + ((lane & 7) ^ ((lane >> 3) & 7)) * 4;
    boff[i] = q * 1024;
  }

  auto stage = [&](int b, int t) {
    char* ab = smem + b * G2_BUF;
    char* bb = ab + 8192;
    const int k0 = t * G2_BK;
    #pragma unroll
    for (int i = 0; i < 2; ++i) gload16(agp[i] + k0, ab + aoff[i]);
    #pragma unroll
    for (int i = 0; i < 4; ++i) gload16(bgp[i] + k0, bb + boff[i]);
  };

  f32x4 acc[4][4];
  #pragma unroll
  for (int mi = 0; mi < 4; ++mi)
    #pragma unroll
    for (int ni = 0; ni < 4; ++ni) acc[mi][ni] = f32x4{0.f,0.f,0.f,0.f};

  auto compute = [&](int b) {
    const char* ab = smem + b * G2_BUF;
    const char* bb = ab + 8192;
    bf16x8 af[4], bf[4];
    const int as = (l4 ^ ((l15 >> 1) & 3)) * 16;
    #pragma unroll
    for (int mi = 0; mi < 4; ++mi) {
      int r = wm * 64 + mi * 16 + l15;
      af[mi] = *(const bf16x8*)(ab + r * 64 + as);
    }
    const int s0 = ((2 * l4) ^ (l15 & 7)) * 16;
    #pragma unroll
    for (int ni = 0; ni < 4; ++ni) {
      int r = wn * 64 + ni * 16 + l15;
      const char* row = bb + r * 128;
      f32x4 b0 = *(const f32x4*)(row + s0);
      f32x4 b1 = *(const f32x4*)(row + (s0 ^ 16));
      bf[ni] = cvt8(b0, b1);
    }
    #pragma unroll
    for (int mi = 0; mi < 4; ++mi)
      #pragma unroll
      for (int ni = 0; ni < 4; ++ni)
        acc[mi][ni] = __builtin_amdgcn_mfma_f32_16x16x32_bf16(af[mi], bf[ni], acc[mi][ni], 0, 0, 0);
  };

  constexpr int NK = I_ / G2_BK;   // 176
  stage(0, 0); stage(1, 1);
  int bs = 2, bc = 0;
  for (int t = 0; t < NK - 2; ++t) {
    __builtin_amdgcn_s_barrier();
    stage(bs, t + 2);
    asm volatile("s_waitcnt vmcnt(12)" ::: "memory");
    __builtin_amdgcn_s_barrier();
    __builtin_amdgcn_sched_barrier(0);
    compute(bc);
    bs = (bs == 2) ? 0 : bs + 1;
    bc = (bc == 2) ? 0 : bc + 1;
  }
  __builtin_amdgcn_s_barrier();
  asm volatile("s_waitcnt vmcnt(6)" ::: "memory");
  __builtin_amdgcn_s_barrier();
  __builtin_amdgcn_sched_barrier(0);
  compute(bc);
  bc = (bc == 2) ? 0 : bc + 1;
  __builtin_amdgcn_s_barrier();
  asm volatile("s_waitcnt vmcnt(0)" ::: "memory");
  __builtin_amdgcn_s_barrier();
  __builtin_amdgcn_sched_barrier(0);
  compute(bc);

  #pragma unroll
  for (int mi = 0; mi < 4; ++mi)
    #pragma unroll
    for (int ni = 0; ni < 4; ++ni)
      #pragma unroll
      for (int j = 0; j < 4; ++j) {
        int rel = wm*64 + mi*16 + l4*4 + j;
        if (m0 + rel < cnt) {
          int col = n0 + wn*64 + ni*16 + l15;
          dpart[(size_t)(off + m0 + rel) * H_ + col] = acc[mi][ni][j];
        }
      }
}

// ================= combine: out[t] = w0*d[s0] + w1*d[s1] =================
__global__ __launch_bounds__(256)
void combine_kernel(const float* __restrict__ dpart, const int* __restrict__ sot,
                    const float* __restrict__ tkw, float* __restrict__ out)
{
  int idx = blockIdx.x * 256 + threadIdx.x;     // T*H/4 total
  int t = idx >> 9;                              // H/4 = 512
  int c = (idx & 511) * 4;
  float wA = tkw[2*t], wB = tkw[2*t+1];
  int sA = sot[2*t], sB = sot[2*t+1];
  float4 a = *(const float4*)(dpart + (size_t)sA * H_ + c);
  float4 b = *(const float4*)(dpart + (size_t)sB * H_ + c);
  float4 o;
  o.x = wA*a.x + wB*b.x; o.y = wA*a.y + wB*b.y;
  o.z = wA*a.z + wB*b.z; o.w = wA*a.w + wB*b.w;
  *(float4*)(out + (size_t)t * H_ + c) = o;
}

extern "C" void kernel_launch(void* const* d_in, const int* in_sizes, int n_in,
                              void* d_out, int out_size, void* d_ws, size_t ws_size,
                              hipStream_t stream) {
  const float* hs = (const float*)d_in[0];
  const float* gw = (const float*)d_in[1];
  const float* w1 = (const float*)d_in[2];
  const float* w2 = (const float*)d_in[3];
  float* out = (float*)d_out;
  char* ws = (char*)d_ws;

  bf16_t* hb    = (bf16_t*)(ws + OFF_HB);
  bf16_t* hout  = (bf16_t*)(ws + OFF_HOUT);
  float*  dpart = (float*) (ws + OFF_DPART);
  int*    tos   = (int*)   (ws + OFF_TOS);
  int*    sot   = (int*)   (ws + OFF_SOT);
  int*    tki   = (int*)   (ws + OFF_TKI);
  float*  tkw   = (float*) (ws + OFF_TKW);
  int*    cnt   = (int*)   (ws + OFF_CNT);
  int*    offp  = (int*)   (ws + OFF_OFFS);
  int*    curp  = (int*)   (ws + OFF_CUR);

  hipMemsetAsync(ws + OFF_CNT, 0, 64, stream);   // zero expert counts each call

  router_kernel<<<T_, 256, 0, stream>>>(hs, gw, tki, tkw, cnt, hb);
  scan_kernel<<<1, 256, 0, stream>>>(cnt, tki, offp, curp, tos, sot);
  gemm1_kernel<<<(T_ / G1_BM) * (I_ / G1_BN) * E_, 256, 0, stream>>>(hb, w1, tos, offp, cnt, hout);
  gemm2_kernel<<<(T_ / G2_BM) * (H_ / G2_BN) * E_, 256, 0, stream>>>(hout, w2, offp, cnt, dpart);
  combine_kernel<<<(T_ * H_ / 4) / 256, 256, 0, stream>>>(dpart, sot, tkw, out);
}